// Round 3
// baseline (184.992 us; speedup 1.0000x reference)
//
#include <hip/hip_runtime.h>
#include <hip/hip_fp16.h>

// Joint bilateral filter, K=5, zero padding, x4-vectorized.
// t: (2,3,720,1280) f32 guide; v: (2,2,720,1280) f32 flow; out: (2,2,720,1280) f32
// coeff = max(0.875 - 50*sum_c (t_c - ts_c)^2, 0); out = sum(vs*coeff)/sum(coeff)

constexpr int H_ = 720;
constexpr int W_ = 1280;
constexpr int HW = H_ * W_;
constexpr float COEF0 = 0.875f;  // 1 - |NEG_SS_DIV|
constexpr float SIDIV = 50.0f;   // 1/(2*0.1^2)

// 320 x-groups (4 px each) * 720 rows * 2 images = 460800 threads = 1800 blocks of 256
__global__ __launch_bounds__(256)
void jbf4(const float* __restrict__ t, const float* __restrict__ v,
          float* __restrict__ out) {
    const int tid = blockIdx.x * 256 + threadIdx.x;
    const int xg  = tid % 320;
    const int rem = tid / 320;
    const int y   = rem % 720;
    const int n   = rem / 720;
    const int x0  = xg * 4;

    const float* tn = t + (size_t)n * 3 * HW;
    const float* vn = v + (size_t)n * 2 * HW;
    float*       on = out + (size_t)n * 2 * HW;

    float num0[4] = {0.f, 0.f, 0.f, 0.f};
    float num1[4] = {0.f, 0.f, 0.f, 0.f};
    float den[4]  = {0.f, 0.f, 0.f, 0.f};
    const int ctr = y * W_ + x0;

    if (xg >= 1 && xg <= 318 && y >= 2 && y <= 717) {
        // -------- interior fast path: all loads in-bounds, 16B aligned --------
        float c0[4], c1[4], c2[4];
        *(float4*)c0 = *(const float4*)(tn + ctr);
        *(float4*)c1 = *(const float4*)(tn + HW + ctr);
        *(float4*)c2 = *(const float4*)(tn + 2 * HW + ctr);

        const float* tb = tn + (y - 2) * W_ + (x0 - 4);
        const float* vb = vn + (y - 2) * W_ + (x0 - 4);
#pragma unroll
        for (int r = 0; r < 5; ++r) {
            // 12-float x-window per channel: cols x0-4 .. x0+7 (need x0-2 .. x0+5)
            float w0[12], w1[12], w2[12], u0[12], u1[12];
            const float* p = tb + r * W_;
            const float* q = vb + r * W_;
#pragma unroll
            for (int s = 0; s < 3; ++s) {
                *(float4*)(w0 + 4 * s) = *(const float4*)(p + 4 * s);
                *(float4*)(w1 + 4 * s) = *(const float4*)(p + HW + 4 * s);
                *(float4*)(w2 + 4 * s) = *(const float4*)(p + 2 * HW + 4 * s);
                *(float4*)(u0 + 4 * s) = *(const float4*)(q + 4 * s);
                *(float4*)(u1 + 4 * s) = *(const float4*)(q + HW + 4 * s);
            }
#pragma unroll
            for (int dx = 0; dx < 5; ++dx) {
#pragma unroll
                for (int j = 0; j < 4; ++j) {
                    const int k = dx + j + 2;           // compile-time index
                    const float d0 = c0[j] - w0[k];
                    const float d1 = c1[j] - w1[k];
                    const float d2 = c2[j] - w2[k];
                    float diff = d0 * d0;
                    diff = fmaf(d1, d1, diff);
                    diff = fmaf(d2, d2, diff);
                    const float c = fmaxf(fmaf(diff, -SIDIV, COEF0), 0.f);
                    num0[j] = fmaf(u0[k], c, num0[j]);
                    num1[j] = fmaf(u1[k], c, num1[j]);
                    den[j] += c;
                }
            }
        }
    } else {
        // -------- boundary path: per-pixel scalar with clamp+select --------
        // OOB taps: ts=0, vs=0 but coeff still accumulates into den (zero pad).
#pragma unroll
        for (int j = 0; j < 4; ++j) {
            const int x = x0 + j;
            const float t0 = tn[ctr + j];
            const float t1 = tn[HW + ctr + j];
            const float t2 = tn[2 * HW + ctr + j];
            for (int dy = 0; dy < 5; ++dy) {
                const int yy = y + dy - 2;
                const bool yin = (unsigned)yy < (unsigned)H_;
                const int yyc = min(max(yy, 0), H_ - 1);
                for (int dx = 0; dx < 5; ++dx) {
                    const int xx = x + dx - 2;
                    const bool in = yin && ((unsigned)xx < (unsigned)W_);
                    const int xxc = min(max(xx, 0), W_ - 1);
                    const int idx = yyc * W_ + xxc;
                    const float s0 = in ? tn[idx] : 0.f;
                    const float s1 = in ? tn[HW + idx] : 0.f;
                    const float s2 = in ? tn[2 * HW + idx] : 0.f;
                    const float w0_ = in ? vn[idx] : 0.f;
                    const float w1_ = in ? vn[HW + idx] : 0.f;
                    const float d0 = t0 - s0, d1 = t1 - s1, d2 = t2 - s2;
                    float diff = d0 * d0;
                    diff = fmaf(d1, d1, diff);
                    diff = fmaf(d2, d2, diff);
                    const float c = fmaxf(fmaf(diff, -SIDIV, COEF0), 0.f);
                    num0[j] = fmaf(w0_, c, num0[j]);
                    num1[j] = fmaf(w1_, c, num1[j]);
                    den[j] += c;
                }
            }
        }
    }

    float4 o0, o1;
    float* o0a = (float*)&o0;
    float* o1a = (float*)&o1;
#pragma unroll
    for (int j = 0; j < 4; ++j) {
        const float r = 1.f / den[j];
        // mimic the reference's fp16 round-trip
        o0a[j] = __half2float(__float2half(num0[j] * r));
        o1a[j] = __half2float(__float2half(num1[j] * r));
    }
    *(float4*)(on + ctr) = o0;
    *(float4*)(on + HW + ctr) = o1;
}

extern "C" void kernel_launch(void* const* d_in, const int* in_sizes, int n_in,
                              void* d_out, int out_size, void* d_ws, size_t ws_size,
                              hipStream_t stream) {
    const float* t = (const float*)d_in[0];
    const float* v = (const float*)d_in[1];
    float* out = (float*)d_out;

    // 2 * 720 * 320 = 460800 threads, exactly 1800 blocks of 256
    jbf4<<<1800, 256, 0, stream>>>(t, v, out);
}

// Round 4
// 41.826 us; speedup vs baseline: 4.4229x; 4.4229x over previous
//
#include <hip/hip_runtime.h>
#include <hip/hip_fp16.h>

// Joint bilateral filter, K=5, zero padding, x4-vectorized, bounded unroll.
// t: (2,3,720,1280) f32 guide; v: (2,2,720,1280) f32 flow; out: (2,2,720,1280) f32
// coeff = max(0.875 - 50*sum_c (t_c - ts_c)^2, 0); out = sum(vs*coeff)/sum(coeff)
//
// All threads run the SAME tap loop; only the 12-wide x-window fill differs
// (interior / left edge / right edge / OOB row -> zeros). Zero-fill is exactly
// the reference's zero-padding: s=0, v=0 but coeff still accumulates into den.
// Row index y is wave-uniform (320 x-groups/row = exactly 5 wave64), so the
// row-validity branch is scalar; x-edge divergence touches load phase only.

constexpr int H_ = 720;
constexpr int W_ = 1280;
constexpr int HW = H_ * W_;
constexpr float COEF0 = 0.875f;  // 1 - |NEG_SS_DIV|
constexpr float SIDIV = 50.0f;   // 1/(2*0.1^2)

__global__ __launch_bounds__(256)
void jbf4(const float* __restrict__ t, const float* __restrict__ v,
          float* __restrict__ out) {
    const int tid = blockIdx.x * 256 + threadIdx.x;
    const int xg  = tid % 320;
    const int rem = tid / 320;
    const int y   = rem % 720;
    const int n   = rem / 720;
    const int x0  = xg * 4;
    const int ctr = y * W_ + x0;

    const float* tn = t + (size_t)n * 3 * HW;
    const float* vn = v + (size_t)n * 2 * HW;
    float*       on = out + (size_t)n * 2 * HW;

    float c0[4], c1[4], c2[4];
    *(float4*)c0 = *(const float4*)(tn + ctr);
    *(float4*)c1 = *(const float4*)(tn + HW + ctr);
    *(float4*)c2 = *(const float4*)(tn + 2 * HW + ctr);

    float num0[4] = {0.f, 0.f, 0.f, 0.f};
    float num1[4] = {0.f, 0.f, 0.f, 0.f};
    float den[4]  = {0.f, 0.f, 0.f, 0.f};

    // window index k <-> image column x0-4+k ; taps use k = dx+j+2 in [2,9]
#pragma unroll 1
    for (int r = 0; r < 5; ++r) {
        const int yy = y + r - 2;
        float w0[12], w1[12], w2[12], u0[12], u1[12];
        const bool yin = (unsigned)yy < (unsigned)H_;   // wave-uniform
        if (yin) {
            const int rb = yy * W_;
            if (xg == 0) {
                // cols 0..7 -> k=4..11 ; k=0..3 (cols -4..-1) = 0
                const float* p = tn + rb;
                const float* q = vn + rb;
#pragma unroll
                for (int s = 0; s < 2; ++s) {
                    *(float4*)(w0 + 4 + 4 * s) = *(const float4*)(p + 4 * s);
                    *(float4*)(w1 + 4 + 4 * s) = *(const float4*)(p + HW + 4 * s);
                    *(float4*)(w2 + 4 + 4 * s) = *(const float4*)(p + 2 * HW + 4 * s);
                    *(float4*)(u0 + 4 + 4 * s) = *(const float4*)(q + 4 * s);
                    *(float4*)(u1 + 4 + 4 * s) = *(const float4*)(q + HW + 4 * s);
                }
#pragma unroll
                for (int k = 0; k < 4; ++k) {
                    w0[k] = 0.f; w1[k] = 0.f; w2[k] = 0.f; u0[k] = 0.f; u1[k] = 0.f;
                }
            } else if (xg == 319) {
                // cols 1272..1279 -> k=0..7 ; k=8..11 (cols 1280..1283) = 0
                const float* p = tn + rb + (W_ - 8);
                const float* q = vn + rb + (W_ - 8);
#pragma unroll
                for (int s = 0; s < 2; ++s) {
                    *(float4*)(w0 + 4 * s) = *(const float4*)(p + 4 * s);
                    *(float4*)(w1 + 4 * s) = *(const float4*)(p + HW + 4 * s);
                    *(float4*)(w2 + 4 * s) = *(const float4*)(p + 2 * HW + 4 * s);
                    *(float4*)(u0 + 4 * s) = *(const float4*)(q + 4 * s);
                    *(float4*)(u1 + 4 * s) = *(const float4*)(q + HW + 4 * s);
                }
#pragma unroll
                for (int k = 8; k < 12; ++k) {
                    w0[k] = 0.f; w1[k] = 0.f; w2[k] = 0.f; u0[k] = 0.f; u1[k] = 0.f;
                }
            } else {
                // interior: cols x0-4 .. x0+7 -> k=0..11, three aligned float4
                const float* p = tn + rb + x0 - 4;
                const float* q = vn + rb + x0 - 4;
#pragma unroll
                for (int s = 0; s < 3; ++s) {
                    *(float4*)(w0 + 4 * s) = *(const float4*)(p + 4 * s);
                    *(float4*)(w1 + 4 * s) = *(const float4*)(p + HW + 4 * s);
                    *(float4*)(w2 + 4 * s) = *(const float4*)(p + 2 * HW + 4 * s);
                    *(float4*)(u0 + 4 * s) = *(const float4*)(q + 4 * s);
                    *(float4*)(u1 + 4 * s) = *(const float4*)(q + HW + 4 * s);
                }
            }
        } else {
            // OOB row: zero pad (taps still accumulate coeff into den)
#pragma unroll
            for (int k = 0; k < 12; ++k) {
                w0[k] = 0.f; w1[k] = 0.f; w2[k] = 0.f; u0[k] = 0.f; u1[k] = 0.f;
            }
        }

        // ---- uniform tap loop: 5 dx * 4 pixels, all compile-time indices ----
#pragma unroll
        for (int dx = 0; dx < 5; ++dx) {
#pragma unroll
            for (int j = 0; j < 4; ++j) {
                const int k = dx + j + 2;
                const float d0 = c0[j] - w0[k];
                const float d1 = c1[j] - w1[k];
                const float d2 = c2[j] - w2[k];
                float diff = d0 * d0;
                diff = fmaf(d1, d1, diff);
                diff = fmaf(d2, d2, diff);
                const float c = fmaxf(fmaf(diff, -SIDIV, COEF0), 0.f);
                num0[j] = fmaf(u0[k], c, num0[j]);
                num1[j] = fmaf(u1[k], c, num1[j]);
                den[j] += c;
            }
        }
    }

    float4 o0, o1;
    float* o0a = (float*)&o0;
    float* o1a = (float*)&o1;
#pragma unroll
    for (int j = 0; j < 4; ++j) {
        const float r = 1.f / den[j];
        // mimic the reference's fp16 round-trip
        o0a[j] = __half2float(__float2half(num0[j] * r));
        o1a[j] = __half2float(__float2half(num1[j] * r));
    }
    *(float4*)(on + ctr) = o0;
    *(float4*)(on + HW + ctr) = o1;
}

extern "C" void kernel_launch(void* const* d_in, const int* in_sizes, int n_in,
                              void* d_out, int out_size, void* d_ws, size_t ws_size,
                              hipStream_t stream) {
    const float* t = (const float*)d_in[0];
    const float* v = (const float*)d_in[1];
    float* out = (float*)d_out;

    // 2 * 720 * 320 = 460800 threads, exactly 1800 blocks of 256
    jbf4<<<1800, 256, 0, stream>>>(t, v, out);
}

// Round 5
// 31.645 us; speedup vs baseline: 5.8458x; 1.3217x over previous
//
#include <hip/hip_runtime.h>
#include <hip/hip_fp16.h>

// Joint bilateral filter, K=5, zero padding, LDS-staged stencil tile.
// t: (2,3,720,1280) f32 guide; v: (2,2,720,1280) f32 flow; out: (2,2,720,1280) f32
// coeff = max(0.875 - 50*sum_c (t_c - ts_c)^2, 0); out = sum(vs*coeff)/sum(coeff)
//
// Block = 256 threads -> output tile 128 cols x 8 rows (32 xg x 4px, 8 rows).
// Stage input region (5 ch x 12 rows x 136 cols, zero-filled halo) into LDS
// once (8 coalesced float4 loads/thread), then all window reads are ds_read_b128.
// Zero-fill halo == reference zero padding (s=0, v=0, coeff still enters den).

constexpr int H_ = 720;
constexpr int W_ = 1280;
constexpr int HW = H_ * W_;
constexpr float COEF0 = 0.875f;  // 1 - |NEG_SS_DIV|
constexpr float SIDIV = 50.0f;   // 1/(2*0.1^2)

constexpr int TC = 136;          // staged cols (gx0-4 .. gx0+131), 16B-aligned
constexpr int TR = 12;           // staged rows (gy0-2 .. gy0+9)
constexpr int NCHUNK = 5 * TR * (TC / 4);   // 2040 float4 chunks; LDS byte = 16*i

__global__ __launch_bounds__(256)
void jbf_lds(const float* __restrict__ t, const float* __restrict__ v,
             float* __restrict__ out) {
    __shared__ float lds[5][TR][TC];        // 32640 B; flat float4 idx == chunk idx

    const int bx = blockIdx.x % 10;         // 10 x-tiles of 128
    const int by = (blockIdx.x / 10) % 90;  // 90 y-tiles of 8
    const int n  = blockIdx.x / 900;        // 2 images
    const int gx0 = bx * 128;
    const int gy0 = by * 8;

    const float* tn = t + (size_t)n * 3 * HW;
    const float* vn = v + (size_t)n * 2 * HW;
    float*       on = out + (size_t)n * 2 * HW;

    const int tid = threadIdx.x;

    // ---------------- stage tile into LDS ----------------
#pragma unroll
    for (int it = 0; it < 8; ++it) {
        const int i = tid + it * 256;
        if (i < NCHUNK) {
            const int c4 = i % 34;           // col chunk (4 floats)
            const int rr = (i / 34) % TR;    // staged row
            const int ch = i / (34 * TR);    // 0..2 = t, 3..4 = v
            const int gy = gy0 - 2 + rr;
            const int gx = gx0 - 4 + 4 * c4; // multiple of 4 -> chunk all-in or all-out
            float4 val = make_float4(0.f, 0.f, 0.f, 0.f);
            if ((unsigned)gy < (unsigned)H_ && (unsigned)gx < (unsigned)(W_ - 3)) {
                const float* src = (ch < 3) ? (tn + (size_t)ch * HW)
                                            : (vn + (size_t)(ch - 3) * HW);
                val = *(const float4*)(src + gy * W_ + gx);
            }
            ((float4*)lds)[i] = val;         // byte 16*i == &lds[ch][rr][4*c4]
        }
    }
    __syncthreads();

    // ---------------- compute 4 px from LDS ----------------
    const int tx = tid & 31;                 // x-group within tile
    const int ty = tid >> 5;                 // output row within tile
    const int lc = 4 * tx;                   // window base col in LDS (k=0 <-> col lc)

    // centers: staged row ty+2, cols lc+4..lc+7
    float c0[4], c1[4], c2[4];
    *(float4*)c0 = *(const float4*)&lds[0][ty + 2][lc + 4];
    *(float4*)c1 = *(const float4*)&lds[1][ty + 2][lc + 4];
    *(float4*)c2 = *(const float4*)&lds[2][ty + 2][lc + 4];

    float num0[4] = {0.f, 0.f, 0.f, 0.f};
    float num1[4] = {0.f, 0.f, 0.f, 0.f};
    float den[4]  = {0.f, 0.f, 0.f, 0.f};

#pragma unroll 1
    for (int r = 0; r < 5; ++r) {
        const int lr = ty + r;
        float w0[12], w1[12], w2[12], u0[12], u1[12];
#pragma unroll
        for (int s = 0; s < 3; ++s) {
            *(float4*)(w0 + 4 * s) = *(const float4*)&lds[0][lr][lc + 4 * s];
            *(float4*)(w1 + 4 * s) = *(const float4*)&lds[1][lr][lc + 4 * s];
            *(float4*)(w2 + 4 * s) = *(const float4*)&lds[2][lr][lc + 4 * s];
            *(float4*)(u0 + 4 * s) = *(const float4*)&lds[3][lr][lc + 4 * s];
            *(float4*)(u1 + 4 * s) = *(const float4*)&lds[4][lr][lc + 4 * s];
        }
#pragma unroll
        for (int dx = 0; dx < 5; ++dx) {
#pragma unroll
            for (int j = 0; j < 4; ++j) {
                const int k = dx + j + 2;    // compile-time index
                const float d0 = c0[j] - w0[k];
                const float d1 = c1[j] - w1[k];
                const float d2 = c2[j] - w2[k];
                float diff = d0 * d0;
                diff = fmaf(d1, d1, diff);
                diff = fmaf(d2, d2, diff);
                const float c = fmaxf(fmaf(diff, -SIDIV, COEF0), 0.f);
                num0[j] = fmaf(u0[k], c, num0[j]);
                num1[j] = fmaf(u1[k], c, num1[j]);
                den[j] += c;
            }
        }
    }

    float4 o0, o1;
    float* o0a = (float*)&o0;
    float* o1a = (float*)&o1;
#pragma unroll
    for (int j = 0; j < 4; ++j) {
        const float rcp = 1.f / den[j];
        // mimic the reference's fp16 round-trip
        o0a[j] = __half2float(__float2half(num0[j] * rcp));
        o1a[j] = __half2float(__float2half(num1[j] * rcp));
    }
    const int ctr = (gy0 + ty) * W_ + gx0 + 4 * tx;
    *(float4*)(on + ctr) = o0;
    *(float4*)(on + HW + ctr) = o1;
}

extern "C" void kernel_launch(void* const* d_in, const int* in_sizes, int n_in,
                              void* d_out, int out_size, void* d_ws, size_t ws_size,
                              hipStream_t stream) {
    const float* t = (const float*)d_in[0];
    const float* v = (const float*)d_in[1];
    float* out = (float*)d_out;

    // 10 x-tiles * 90 y-tiles * 2 images = 1800 blocks of 256
    jbf_lds<<<1800, 256, 0, stream>>>(t, v, out);
}